// Round 4
// baseline (5786.303 us; speedup 1.0000x reference)
//
#include <hip/hip_runtime.h>
#include <hip/hip_bf16.h>

typedef unsigned short u16;
typedef short bf16x8 __attribute__((ext_vector_type(8)));   // 8 bf16 (4 VGPRs) MFMA frag
typedef float floatx4 __attribute__((ext_vector_type(4)));  // MFMA acc

#define B_DIM 2048
#define F_DIM 4096
#define H_DIM 1024
#define NSTEP 64

__device__ __forceinline__ float fast_tanh(float x) {
    return 1.0f - 2.0f / (__expf(2.0f * x) + 1.0f);
}

// fp32 -> bf16 RNE via compiler cast (emits v_cvt_pk_bf16_f32 for pairs)
__device__ __forceinline__ u16 f2b(float x) {
    union { __hip_bfloat16 b; u16 u; } v;
    v.b = __float2bfloat16(x);
    return v.u;
}

template<int F32>
__device__ __forceinline__ int4 ld8(const void* base, size_t elemOff) {
    if constexpr (F32) {
        const float* p = (const float*)base + elemOff;
        float4 lo = *(const float4*)p;
        float4 hi = *(const float4*)(p + 4);
        union { u16 h[8]; int4 v; } rr;
        rr.h[0] = f2b(lo.x); rr.h[1] = f2b(lo.y); rr.h[2] = f2b(lo.z); rr.h[3] = f2b(lo.w);
        rr.h[4] = f2b(hi.x); rr.h[5] = f2b(hi.y); rr.h[6] = f2b(hi.z); rr.h[7] = f2b(hi.w);
        return rr.v;
    } else {
        return *(const int4*)((const u16*)base + elemOff);
    }
}

// ---------------- batched/selector GEMM for the parallel (MLP/pre) phase ----------------
// C[z] = act(A[z] @ W[z]^T + bias1[z]); grid must be (16, 32, z). BM=BN=BK=64, 256 thr.
template<int AF32, int WF32, int ACT, int OUT_F32>
__global__ __launch_bounds__(256)
void gemm64(const void* __restrict__ A0, const void* __restrict__ A1, const void* __restrict__ A2,
            const void* __restrict__ Wp0, const void* __restrict__ Wp1, const void* __restrict__ Wp2,
            const float* __restrict__ bia0, const float* __restrict__ bia1, const float* __restrict__ bia2,
            void* __restrict__ C0, void* __restrict__ C1, void* __restrict__ C2,
            const int N, const int K)
{
    constexpr int BM = 64, BN = 64, BK = 64, LS = 72;
    __shared__ u16 As[2][BM * LS];
    __shared__ u16 Bs[2][BN * LS];

    const int z = blockIdx.z;
    const void*  A     = (z == 0) ? A0 : (z == 1) ? A1 : A2;
    const void*  W     = (z == 0) ? Wp0 : (z == 1) ? Wp1 : Wp2;
    const float* bias1 = (z == 0) ? bia0 : (z == 1) ? bia1 : bia2;
    void*        Cout  = (z == 0) ? C0 : (z == 1) ? C1 : C2;

    const int tid  = threadIdx.x;
    const int wave = tid >> 6, lane = tid & 63;
    const int wm = wave >> 1, wn = wave & 1;
    const int r = lane & 15, q = lane >> 4;

    const int lin = blockIdx.y * 16 + blockIdx.x;
    const int mti = (lin & 7) | ((lin >> 7) << 3);
    const int nti = (lin >> 3) & 15;
    const int m0 = mti * BM, n0 = nti * BN;

    floatx4 acc[2][2];
    const floatx4 zf = {0.f, 0.f, 0.f, 0.f};
    #pragma unroll
    for (int a = 0; a < 2; a++)
        #pragma unroll
        for (int b = 0; b < 2; b++) acc[a][b] = zf;

    const int row0 = tid >> 3, kc = (tid & 7) << 3, row1 = row0 + 32;
    const size_t aOff0 = (size_t)(m0 + row0) * K + kc;
    const size_t aOff1 = (size_t)(m0 + row1) * K + kc;
    const size_t wOff0 = (size_t)(n0 + row0) * K + kc;
    const size_t wOff1 = (size_t)(n0 + row1) * K + kc;

    int4 av0 = ld8<AF32>(A, aOff0);
    int4 av1 = ld8<AF32>(A, aOff1);
    int4 bv0 = ld8<WF32>(W, wOff0);
    int4 bv1 = ld8<WF32>(W, wOff1);

    int p = 0;
    for (int kb = 0; kb < K; kb += BK) {
        *(int4*)&As[p][row0 * LS + kc] = av0;
        *(int4*)&As[p][row1 * LS + kc] = av1;
        *(int4*)&Bs[p][row0 * LS + kc] = bv0;
        *(int4*)&Bs[p][row1 * LS + kc] = bv1;
        __syncthreads();
        if (kb + BK < K) {
            av0 = ld8<AF32>(A, aOff0 + kb + BK);
            av1 = ld8<AF32>(A, aOff1 + kb + BK);
            bv0 = ld8<WF32>(W, wOff0 + kb + BK);
            bv1 = ld8<WF32>(W, wOff1 + kb + BK);
        }
        bf16x8 af[2][2], bfr[2][2];
        #pragma unroll
        for (int ks = 0; ks < 2; ks++)
            #pragma unroll
            for (int t = 0; t < 2; t++) {
                af[ks][t]  = *(const bf16x8*)&As[p][(wm * 32 + t * 16 + r) * LS + ks * 32 + q * 8];
                bfr[ks][t] = *(const bf16x8*)&Bs[p][(wn * 32 + t * 16 + r) * LS + ks * 32 + q * 8];
            }
        #pragma unroll
        for (int ks = 0; ks < 2; ks++)
            #pragma unroll
            for (int mt = 0; mt < 2; mt++)
                #pragma unroll
                for (int nt = 0; nt < 2; nt++)
                    acc[mt][nt] = __builtin_amdgcn_mfma_f32_16x16x32_bf16(af[ks][mt], bfr[ks][nt], acc[mt][nt], 0, 0, 0);
        p ^= 1;
    }

    #pragma unroll
    for (int mt = 0; mt < 2; mt++)
        #pragma unroll
        for (int nt = 0; nt < 2; nt++) {
            const int col  = n0 + wn * 32 + nt * 16 + r;
            const int rowb = m0 + wm * 32 + mt * 16 + q * 4;
            const float bb = bias1 ? bias1[col] : 0.f;
            #pragma unroll
            for (int i = 0; i < 4; i++) {
                float v = acc[mt][nt][i] + bb;
                if (ACT == 1) v = fmaxf(v, 0.f);
                if (OUT_F32) ((float*)Cout)[(size_t)(rowb + i) * N + col] = v;
                else ((u16*)Cout)[(size_t)(rowb + i) * N + col] = f2b(v);
            }
        }
}

// ---------------- persistent RNN: all 64 steps in ONE launch ----------------
// Grid 512 blocks x 256 thr. Residency: 64 KiB LDS -> exactly 2 blocks/CU x 256 CU = 512
// (grid == device capacity; device idle at dispatch -> all WGs co-resident), and
// __launch_bounds__(256,2) caps VGPR<=256 so registers can't lower it. No cooperative
// API (graph-capture-safe). Step dependency is GROUP-LOCAL: rows [m0,m0+64) of step s
// are written and read only by the 16 blocks sharing mti -> per-group monotonic atomic
// barrier (16 arrivals/step). Monotonic counter never blocks on graph replay (re-zeroed
// by captured memset each run).
__global__ __launch_bounds__(256, 2)
void rnn_persist(u16* __restrict__ bufA, u16* __restrict__ bufB,
                 const u16* __restrict__ Wsum, const u16* __restrict__ Whhb,
                 const float* __restrict__ bsum, const float* __restrict__ bhh,
                 const float* __restrict__ pre_xh, const float* __restrict__ pre_xm,
                 const float* __restrict__ pre_xl,
                 const float* __restrict__ Wact, float* __restrict__ logits,
                 float* __restrict__ outHx, unsigned* __restrict__ gsync)
{
    constexpr int BM = 64, BN = 64, BK = 128, K = H_DIM, N = H_DIM;
    __shared__ u16 As[2][BM * BK];   // 32 KiB
    __shared__ u16 Bs[2][BN * BK];   // 32 KiB

    const int tid  = threadIdx.x;
    const int wave = tid >> 6, lane = tid & 63;
    const int wm = wave >> 1, wn = wave & 1;
    const int r = lane & 15, q = lane >> 4;

    const int lin = blockIdx.x;
    const int mti = (lin & 7) | ((lin >> 7) << 3);   // group: 16 blocks share mti
    const int nti = (lin >> 3) & 15;
    const int m0 = mti * BM, n0 = nti * BN;

    // staging: 64 rows x 128 cols; 4 threads/row, 4 x 16B chunks, XOR-swizzled LDS
    const int row = tid >> 2, c = tid & 3;
    const size_t aOff = (size_t)(m0 + row) * K + c * 8;
    const size_t wOff = (size_t)(n0 + row) * K + c * 8;
    int dst[4];
    #pragma unroll
    for (int j = 0; j < 4; j++)
        dst[j] = row * BK + (((c * 8) + j * 32) ^ ((row & 7) * 8));
    const int sw = (r & 7) * 8;

    unsigned* cnt = gsync + mti * 32;   // 128-B padded counter per group

    const u16* cur = bufA;
    u16* nxt = bufB;

    for (int s = 0; s < NSTEP; ++s) {
        const u16* W; const float* bias; const float* pre = nullptr;
        if (s == 15)                 { W = Whhb; bias = bhh; pre = pre_xh; }
        else if (s == 21 || s == 37) { W = Whhb; bias = bhh; pre = pre_xm; }
        else if (s == 42 || s == 58) { W = Whhb; bias = bhh; pre = pre_xl; }
        else                         { W = Wsum; bias = bsum; }
        const bool last = (s == NSTEP - 1);

        floatx4 acc[2][2];
        const floatx4 zf = {0.f, 0.f, 0.f, 0.f};
        acc[0][0] = zf; acc[0][1] = zf; acc[1][0] = zf; acc[1][1] = zf;

        int4 av[4], bv[4];
        #pragma unroll
        for (int j = 0; j < 4; j++) {
            av[j] = *(const int4*)(cur + aOff + j * 32);
            bv[j] = *(const int4*)(W + wOff + j * 32);
        }

        int p = 0;
        for (int kb = 0; kb < K; kb += BK) {
            #pragma unroll
            for (int j = 0; j < 4; j++) {
                *(int4*)&As[p][dst[j]] = av[j];
                *(int4*)&Bs[p][dst[j]] = bv[j];
            }
            __syncthreads();
            if (kb + BK < K) {
                #pragma unroll
                for (int j = 0; j < 4; j++) {
                    av[j] = *(const int4*)(cur + aOff + kb + BK + j * 32);
                    bv[j] = *(const int4*)(W + wOff + kb + BK + j * 32);
                }
            }
            #pragma unroll
            for (int ks = 0; ks < 4; ks++) {
                const int cb = ((ks * 32) + q * 8) ^ sw;
                bf16x8 a0 = *(const bf16x8*)&As[p][(wm * 32 +      r) * BK + cb];
                bf16x8 a1 = *(const bf16x8*)&As[p][(wm * 32 + 16 + r) * BK + cb];
                bf16x8 b0 = *(const bf16x8*)&Bs[p][(wn * 32 +      r) * BK + cb];
                bf16x8 b1 = *(const bf16x8*)&Bs[p][(wn * 32 + 16 + r) * BK + cb];
                acc[0][0] = __builtin_amdgcn_mfma_f32_16x16x32_bf16(a0, b0, acc[0][0], 0, 0, 0);
                acc[0][1] = __builtin_amdgcn_mfma_f32_16x16x32_bf16(a0, b1, acc[0][1], 0, 0, 0);
                acc[1][0] = __builtin_amdgcn_mfma_f32_16x16x32_bf16(a1, b0, acc[1][0], 0, 0, 0);
                acc[1][1] = __builtin_amdgcn_mfma_f32_16x16x32_bf16(a1, b1, acc[1][1], 0, 0, 0);
            }
            p ^= 1;
        }

        // Epilogue. C/D layout: row = q*4+i, col = r.
        const int col0 = n0 + wn * 32 + r;
        const int col1 = col0 + 16;
        const float bb0 = bias[col0], bb1 = bias[col1];
        const float wa0 = Wact[col0], wa1 = Wact[col1];
        #pragma unroll
        for (int mt = 0; mt < 2; mt++) {
            const int rowb = m0 + wm * 32 + mt * 16 + q * 4;
            #pragma unroll
            for (int i = 0; i < 4; i++) {
                float v0 = acc[mt][0][i] + bb0;
                float v1 = acc[mt][1][i] + bb1;
                if (pre) {
                    v0 += pre[(size_t)(rowb + i) * N + col0];
                    v1 += pre[(size_t)(rowb + i) * N + col1];
                }
                v0 = fast_tanh(v0);
                v1 = fast_tanh(v1);
                if (last) {
                    outHx[(size_t)(rowb + i) * N + col0] = v0;
                    outHx[(size_t)(rowb + i) * N + col1] = v1;
                } else {
                    nxt[(size_t)(rowb + i) * N + col0] = f2b(v0);
                    nxt[(size_t)(rowb + i) * N + col1] = f2b(v1);
                }
                acc[mt][0][i] = v0;
                acc[mt][1][i] = v1;
            }
        }

        // Actor head partial: shuffle-reduce 32 cols -> LDS -> 64 atomics/block
        __syncthreads();                  // all frag reads done; reuse As as scratch
        float* sc = (float*)As;
        #pragma unroll
        for (int mt = 0; mt < 2; mt++)
            #pragma unroll
            for (int i = 0; i < 4; i++) {
                float v = acc[mt][0][i] * wa0 + acc[mt][1][i] * wa1;
                v += __shfl_xor(v, 1);
                v += __shfl_xor(v, 2);
                v += __shfl_xor(v, 4);
                v += __shfl_xor(v, 8);
                if (r == 0) sc[wn * 64 + wm * 32 + mt * 16 + q * 4 + i] = v;
            }
        __syncthreads();
        if (tid < 64) {
            float v = sc[tid] + sc[64 + tid];
            atomicAdd(&logits[(size_t)s * B_DIM + m0 + tid], v);
        }

        if (!last) {
            // ---- group barrier (release: hx stores visible; acquire: see peers' stores) ----
            __threadfence();              // each thread flushes its hx stores (agent scope)
            __syncthreads();              // all threads of block have fenced
            if (tid == 0) {
                __hip_atomic_fetch_add(cnt, 1u, __ATOMIC_RELAXED, __HIP_MEMORY_SCOPE_AGENT);
                const unsigned tgt = 16u * (unsigned)(s + 1);
                while (__hip_atomic_load(cnt, __ATOMIC_RELAXED, __HIP_MEMORY_SCOPE_AGENT) < tgt)
                    __builtin_amdgcn_s_sleep(2);
            }
            __syncthreads();
            __threadfence();              // invalidate stale caches before next-step loads
            const u16* t = cur; cur = nxt; nxt = (u16*)t;
        }
    }
}

// Wsum = bf16(W_ih+W_hh), Whhb = bf16(W_hh), Wihb = bf16(W_ih); bsum = b_ih + b_hh
__global__ void prep_w(const float* __restrict__ Wih, const float* __restrict__ Whh,
                       u16* __restrict__ Wsum, u16* __restrict__ Whhb, u16* __restrict__ Wihb,
                       const float* __restrict__ bih, const float* __restrict__ bhh,
                       float* __restrict__ bsum, int n) {
    int i = blockIdx.x * 256 + threadIdx.x;
    if (i < n) {
        float a = Wih[i], b = Whh[i];
        Wsum[i] = f2b(a + b);
        Whhb[i] = f2b(b);
        Wihb[i] = f2b(a);
    }
    if (i < H_DIM) bsum[i] = bih[i] + bhh[i];
}

__global__ void sigmoid_kernel(const float* __restrict__ logits, const float* __restrict__ b_act,
                               float* __restrict__ out, int n) {
    int i = blockIdx.x * 256 + threadIdx.x;
    if (i < n) {
        float zv = logits[i] + b_act[0];
        out[i] = 1.0f / (1.0f + __expf(-zv));
    }
}

extern "C" void kernel_launch(void* const* d_in, const int* in_sizes, int n_in,
                              void* d_out, int out_size, void* d_ws, size_t ws_size,
                              hipStream_t stream) {
    (void)in_sizes; (void)n_in; (void)out_size; (void)ws_size;
    const int Bn = B_DIM, F = F_DIM, H = H_DIM;

    const float* xin[3] = {(const float*)d_in[0], (const float*)d_in[1], (const float*)d_in[2]};
    const float* W1[3]  = {(const float*)d_in[3], (const float*)d_in[7], (const float*)d_in[11]};
    const float* b1[3]  = {(const float*)d_in[4], (const float*)d_in[8], (const float*)d_in[12]};
    const float* W2[3]  = {(const float*)d_in[5], (const float*)d_in[9], (const float*)d_in[13]};
    const float* b2[3]  = {(const float*)d_in[6], (const float*)d_in[10], (const float*)d_in[14]};
    const float* W_ih   = (const float*)d_in[15];
    const float* W_hh   = (const float*)d_in[16];
    const float* b_ih   = (const float*)d_in[17];
    const float* b_hh   = (const float*)d_in[18];
    const float* W_act  = (const float*)d_in[19];
    const float* b_act  = (const float*)d_in[20];

    // ws layout (phased overlaps; peak ~47 MB)
    const size_t MB = 1024 * 1024;
    char* ws = (char*)d_ws;
    u16*   xl     = (u16*)(ws + 0 * MB);
    u16*   xm     = (u16*)(ws + 4 * MB);
    u16*   xh     = (u16*)(ws + 8 * MB);    // hx ping
    u16*   hxB    = (u16*)(ws + 12 * MB);   // hx pong
    u16*   Wsum   = (u16*)(ws + 16 * MB);
    u16*   Whhb   = (u16*)(ws + 18 * MB);
    u16*   Wihb   = (u16*)(ws + 20 * MB);
    u16*   h1a    = (u16*)(ws + 22 * MB);   // live fc1 -> fc2
    u16*   h1b    = (u16*)(ws + 26 * MB);
    u16*   h1c    = (u16*)(ws + 30 * MB);
    float* pre_xh = (float*)(ws + 22 * MB); // written after fc2 (h1 dead)
    float* pre_xm = (float*)(ws + 30 * MB); // overlaps h1c (dead by then)
    float* pre_xl = (float*)(ws + 38 * MB);
    float* logits = (float*)(ws + 46 * MB);                        // 512 KB
    float* bsum   = (float*)(ws + 46 * MB + 512 * 1024);           // 4 KB
    unsigned* gsync = (unsigned*)(ws + 46 * MB + 516 * 1024);      // 4 KB (32 groups x 128 B)

    dim3 blk(256);
    dim3 grid3(16, 32, 3);

    (void)hipMemsetAsync(logits, 0, (size_t)NSTEP * Bn * sizeof(float), stream);
    (void)hipMemsetAsync(gsync, 0, 4096, stream);
    prep_w<<<dim3((H * H + 255) / 256), blk, 0, stream>>>(W_ih, W_hh, Wsum, Whhb, Wihb,
                                                          b_ih, b_hh, bsum, H * H);

    // fc1: all three branches in ONE z=3 launch; fp32 operands converted in-kernel
    u16* h1[3] = {h1a, h1b, h1c};
    gemm64<1,1,1,0><<<grid3, blk, 0, stream>>>(
        xin[0], xin[1], xin[2], W1[0], W1[1], W1[2], b1[0], b1[1], b1[2],
        h1[0], h1[1], h1[2], H, F);
    // fc2: batched, W2 fp32 converted in-kernel
    gemm64<0,1,1,0><<<grid3, blk, 0, stream>>>(
        h1a, h1b, h1c, W2[0], W2[1], W2[2], b2[0], b2[1], b2[2],
        xl, xm, xh, H, H);
    // pre (batched): pre_* = {xh,xm,xl} @ W_ih^T + b_ih (fp32 out)
    gemm64<0,0,0,1><<<grid3, blk, 0, stream>>>(
        xh, xm, xl, Wihb, Wihb, Wihb, b_ih, b_ih, b_ih,
        pre_xh, pre_xm, pre_xl, H, H);

    // persistent RNN: one plain launch (512 blocks == exact device capacity at 64 KiB LDS)
    float* outHx = (float*)d_out + (size_t)NSTEP * Bn;
    rnn_persist<<<dim3(512), dim3(256), 0, stream>>>(
        xh, hxB, Wsum, Whhb, bsum, b_hh, pre_xh, pre_xm, pre_xl,
        W_act, logits, outHx, gsync);

    sigmoid_kernel<<<dim3((NSTEP * Bn + 255) / 256), blk, 0, stream>>>(
        logits, b_act, (float*)d_out, NSTEP * Bn);
}

// Round 5
// 1337.772 us; speedup vs baseline: 4.3253x; 4.3253x over previous
//
#include <hip/hip_runtime.h>
#include <hip/hip_bf16.h>

typedef unsigned short u16;
typedef short bf16x8 __attribute__((ext_vector_type(8)));   // 8 bf16 (4 VGPRs) MFMA frag
typedef float floatx4 __attribute__((ext_vector_type(4)));  // MFMA acc

#define B_DIM 2048
#define F_DIM 4096
#define H_DIM 1024
#define NSTEP 64

__device__ __forceinline__ float fast_tanh(float x) {
    return 1.0f - 2.0f / (__expf(2.0f * x) + 1.0f);
}

// fp32 -> bf16 RNE via compiler cast (emits v_cvt_pk_bf16_f32 for pairs)
__device__ __forceinline__ u16 f2b(float x) {
    union { __hip_bfloat16 b; u16 u; } v;
    v.b = __float2bfloat16(x);
    return v.u;
}

// ---- device-scope (cross-XCD-coherent) memory ops: bypass L1/L2, hit the memory-side
// Infinity Cache (the device coherence point). No wbl2/inv cache-maintenance needed.
__device__ __forceinline__ void ldg16_dev(int4& d, const void* p) {
    asm volatile("global_load_dwordx4 %0, %1, off sc0 sc1" : "=v"(d) : "v"(p));
}
__device__ __forceinline__ void ldg16(int4& d, const void* p) {
    asm volatile("global_load_dwordx4 %0, %1, off" : "=v"(d) : "v"(p));
}
__device__ __forceinline__ void stg2_dev(void* p, unsigned v) {
    asm volatile("global_store_short %0, %1, off sc0 sc1" :: "v"(p), "v"(v) : "memory");
}
// wait for ALL outstanding vmem (my asm loads + stores); sched_barrier pins it (rule #18)
#define VMEM_DRAIN() do { asm volatile("s_waitcnt vmcnt(0)" ::: "memory"); \
                          __builtin_amdgcn_sched_barrier(0); } while (0)

template<int F32>
__device__ __forceinline__ int4 ld8(const void* base, size_t elemOff) {
    if constexpr (F32) {
        const float* p = (const float*)base + elemOff;
        float4 lo = *(const float4*)p;
        float4 hi = *(const float4*)(p + 4);
        union { u16 h[8]; int4 v; } rr;
        rr.h[0] = f2b(lo.x); rr.h[1] = f2b(lo.y); rr.h[2] = f2b(lo.z); rr.h[3] = f2b(lo.w);
        rr.h[4] = f2b(hi.x); rr.h[5] = f2b(hi.y); rr.h[6] = f2b(hi.z); rr.h[7] = f2b(hi.w);
        return rr.v;
    } else {
        return *(const int4*)((const u16*)base + elemOff);
    }
}

// ---------------- batched/selector GEMM for the parallel (MLP/pre) phase ----------------
// C[z] = act(A[z] @ W[z]^T + bias1[z]); grid must be (16, 32, z). BM=BN=BK=64, 256 thr.
template<int AF32, int WF32, int ACT, int OUT_F32>
__global__ __launch_bounds__(256)
void gemm64(const void* __restrict__ A0, const void* __restrict__ A1, const void* __restrict__ A2,
            const void* __restrict__ Wp0, const void* __restrict__ Wp1, const void* __restrict__ Wp2,
            const float* __restrict__ bia0, const float* __restrict__ bia1, const float* __restrict__ bia2,
            void* __restrict__ C0, void* __restrict__ C1, void* __restrict__ C2,
            const int N, const int K)
{
    constexpr int BM = 64, BN = 64, BK = 64, LS = 72;
    __shared__ u16 As[2][BM * LS];
    __shared__ u16 Bs[2][BN * LS];

    const int z = blockIdx.z;
    const void*  A     = (z == 0) ? A0 : (z == 1) ? A1 : A2;
    const void*  W     = (z == 0) ? Wp0 : (z == 1) ? Wp1 : Wp2;
    const float* bias1 = (z == 0) ? bia0 : (z == 1) ? bia1 : bia2;
    void*        Cout  = (z == 0) ? C0 : (z == 1) ? C1 : C2;

    const int tid  = threadIdx.x;
    const int wave = tid >> 6, lane = tid & 63;
    const int wm = wave >> 1, wn = wave & 1;
    const int r = lane & 15, q = lane >> 4;

    const int lin = blockIdx.y * 16 + blockIdx.x;
    const int mti = (lin & 7) | ((lin >> 7) << 3);
    const int nti = (lin >> 3) & 15;
    const int m0 = mti * BM, n0 = nti * BN;

    floatx4 acc[2][2];
    const floatx4 zf = {0.f, 0.f, 0.f, 0.f};
    #pragma unroll
    for (int a = 0; a < 2; a++)
        #pragma unroll
        for (int b = 0; b < 2; b++) acc[a][b] = zf;

    const int row0 = tid >> 3, kc = (tid & 7) << 3, row1 = row0 + 32;
    const size_t aOff0 = (size_t)(m0 + row0) * K + kc;
    const size_t aOff1 = (size_t)(m0 + row1) * K + kc;
    const size_t wOff0 = (size_t)(n0 + row0) * K + kc;
    const size_t wOff1 = (size_t)(n0 + row1) * K + kc;

    int4 av0 = ld8<AF32>(A, aOff0);
    int4 av1 = ld8<AF32>(A, aOff1);
    int4 bv0 = ld8<WF32>(W, wOff0);
    int4 bv1 = ld8<WF32>(W, wOff1);

    int p = 0;
    for (int kb = 0; kb < K; kb += BK) {
        *(int4*)&As[p][row0 * LS + kc] = av0;
        *(int4*)&As[p][row1 * LS + kc] = av1;
        *(int4*)&Bs[p][row0 * LS + kc] = bv0;
        *(int4*)&Bs[p][row1 * LS + kc] = bv1;
        __syncthreads();
        if (kb + BK < K) {
            av0 = ld8<AF32>(A, aOff0 + kb + BK);
            av1 = ld8<AF32>(A, aOff1 + kb + BK);
            bv0 = ld8<WF32>(W, wOff0 + kb + BK);
            bv1 = ld8<WF32>(W, wOff1 + kb + BK);
        }
        bf16x8 af[2][2], bfr[2][2];
        #pragma unroll
        for (int ks = 0; ks < 2; ks++)
            #pragma unroll
            for (int t = 0; t < 2; t++) {
                af[ks][t]  = *(const bf16x8*)&As[p][(wm * 32 + t * 16 + r) * LS + ks * 32 + q * 8];
                bfr[ks][t] = *(const bf16x8*)&Bs[p][(wn * 32 + t * 16 + r) * LS + ks * 32 + q * 8];
            }
        #pragma unroll
        for (int ks = 0; ks < 2; ks++)
            #pragma unroll
            for (int mt = 0; mt < 2; mt++)
                #pragma unroll
                for (int nt = 0; nt < 2; nt++)
                    acc[mt][nt] = __builtin_amdgcn_mfma_f32_16x16x32_bf16(af[ks][mt], bfr[ks][nt], acc[mt][nt], 0, 0, 0);
        p ^= 1;
    }

    #pragma unroll
    for (int mt = 0; mt < 2; mt++)
        #pragma unroll
        for (int nt = 0; nt < 2; nt++) {
            const int col  = n0 + wn * 32 + nt * 16 + r;
            const int rowb = m0 + wm * 32 + mt * 16 + q * 4;
            const float bb = bias1 ? bias1[col] : 0.f;
            #pragma unroll
            for (int i = 0; i < 4; i++) {
                float v = acc[mt][nt][i] + bb;
                if (ACT == 1) v = fmaxf(v, 0.f);
                if (OUT_F32) ((float*)Cout)[(size_t)(rowb + i) * N + col] = v;
                else ((u16*)Cout)[(size_t)(rowb + i) * N + col] = f2b(v);
            }
        }
}

// ---------------- persistent RNN: all 64 steps in ONE launch ----------------
// Grid 512 blocks x 256 thr; 64 KiB LDS -> exactly 2 blocks/CU x 256 CU = 512 co-resident.
// Coherence WITHOUT cache-maintenance: hx ping-pong buffers are written with
// device-scope write-through stores (sc0 sc1 -> land in memory-side Infinity Cache) and
// read with device-scope loads (sc0 sc1 -> bypass L1/L2). Correct under ANY block->XCD
// placement; zero buffer_wbl2/buffer_inv (round-4's 85 us/step TCC-walk convoy).
// W/bias/pre are read-only during the kernel -> plain cached loads.
// Per-group (16 blocks sharing mti) monotonic atomic barrier; release = vmcnt(0) drain
// of the sc1 stores before the arrival add.
__global__ __launch_bounds__(256, 2)
void rnn_persist(u16* __restrict__ bufA, u16* __restrict__ bufB,
                 const u16* __restrict__ Wsum, const u16* __restrict__ Whhb,
                 const float* __restrict__ bsum, const float* __restrict__ bhh,
                 const float* __restrict__ pre_xh, const float* __restrict__ pre_xm,
                 const float* __restrict__ pre_xl,
                 const float* __restrict__ Wact, float* __restrict__ logits,
                 float* __restrict__ outHx, unsigned* __restrict__ gsync)
{
    constexpr int BM = 64, BN = 64, BK = 128, K = H_DIM, N = H_DIM;
    __shared__ u16 As[2][BM * BK];   // 32 KiB
    __shared__ u16 Bs[2][BN * BK];   // 32 KiB

    const int tid  = threadIdx.x;
    const int wave = tid >> 6, lane = tid & 63;
    const int wm = wave >> 1, wn = wave & 1;
    const int r = lane & 15, q = lane >> 4;

    const int lin = blockIdx.x;
    const int mti = (lin & 7) | ((lin >> 7) << 3);   // group: 16 blocks share mti
    const int nti = (lin >> 3) & 15;
    const int m0 = mti * BM, n0 = nti * BN;

    // staging: 64 rows x 128 cols; 4 threads/row, 4 x 16B chunks, XOR-swizzled LDS
    const int row = tid >> 2, c = tid & 3;
    const size_t aOff = (size_t)(m0 + row) * K + c * 8;
    const size_t wOff = (size_t)(n0 + row) * K + c * 8;
    int dst[4];
    #pragma unroll
    for (int j = 0; j < 4; j++)
        dst[j] = row * BK + (((c * 8) + j * 32) ^ ((row & 7) * 8));
    const int sw = (r & 7) * 8;

    unsigned* cnt = gsync + mti * 32;   // 128-B padded counter per group

    const u16* cur = bufA;
    u16* nxt = bufB;

    for (int s = 0; s < NSTEP; ++s) {
        const u16* W; const float* bias; const float* pre = nullptr;
        if (s == 15)                 { W = Whhb; bias = bhh; pre = pre_xh; }
        else if (s == 21 || s == 37) { W = Whhb; bias = bhh; pre = pre_xm; }
        else if (s == 42 || s == 58) { W = Whhb; bias = bhh; pre = pre_xl; }
        else                         { W = Wsum; bias = bsum; }
        const bool last = (s == NSTEP - 1);

        floatx4 acc[2][2];
        const floatx4 zf = {0.f, 0.f, 0.f, 0.f};
        acc[0][0] = zf; acc[0][1] = zf; acc[1][0] = zf; acc[1][1] = zf;

        int4 av[4], bv[4];
        #pragma unroll
        for (int j = 0; j < 4; j++) {
            ldg16_dev(av[j], cur + aOff + j * 32);   // hx: device-coherent read
            ldg16(bv[j], W + wOff + j * 32);          // W: plain cached read
        }

        int p = 0;
        for (int kb = 0; kb < K; kb += BK) {
            VMEM_DRAIN();                // av/bv data ready (all staging loads are asm)
            #pragma unroll
            for (int j = 0; j < 4; j++) {
                *(int4*)&As[p][dst[j]] = av[j];
                *(int4*)&Bs[p][dst[j]] = bv[j];
            }
            __syncthreads();
            if (kb + BK < K) {
                #pragma unroll
                for (int j = 0; j < 4; j++) {
                    ldg16_dev(av[j], cur + aOff + kb + BK + j * 32);
                    ldg16(bv[j], W + wOff + kb + BK + j * 32);
                }
            }
            #pragma unroll
            for (int ks = 0; ks < 4; ks++) {
                const int cb = ((ks * 32) + q * 8) ^ sw;
                bf16x8 a0 = *(const bf16x8*)&As[p][(wm * 32 +      r) * BK + cb];
                bf16x8 a1 = *(const bf16x8*)&As[p][(wm * 32 + 16 + r) * BK + cb];
                bf16x8 b0 = *(const bf16x8*)&Bs[p][(wn * 32 +      r) * BK + cb];
                bf16x8 b1 = *(const bf16x8*)&Bs[p][(wn * 32 + 16 + r) * BK + cb];
                acc[0][0] = __builtin_amdgcn_mfma_f32_16x16x32_bf16(a0, b0, acc[0][0], 0, 0, 0);
                acc[0][1] = __builtin_amdgcn_mfma_f32_16x16x32_bf16(a0, b1, acc[0][1], 0, 0, 0);
                acc[1][0] = __builtin_amdgcn_mfma_f32_16x16x32_bf16(a1, b0, acc[1][0], 0, 0, 0);
                acc[1][1] = __builtin_amdgcn_mfma_f32_16x16x32_bf16(a1, b1, acc[1][1], 0, 0, 0);
            }
            p ^= 1;
        }

        // Epilogue. C/D layout: row = q*4+i, col = r.
        const int col0 = n0 + wn * 32 + r;
        const int col1 = col0 + 16;
        const float bb0 = bias[col0], bb1 = bias[col1];
        const float wa0 = Wact[col0], wa1 = Wact[col1];
        #pragma unroll
        for (int mt = 0; mt < 2; mt++) {
            const int rowb = m0 + wm * 32 + mt * 16 + q * 4;
            #pragma unroll
            for (int i = 0; i < 4; i++) {
                float v0 = acc[mt][0][i] + bb0;
                float v1 = acc[mt][1][i] + bb1;
                if (pre) {
                    v0 += pre[(size_t)(rowb + i) * N + col0];
                    v1 += pre[(size_t)(rowb + i) * N + col1];
                }
                v0 = fast_tanh(v0);
                v1 = fast_tanh(v1);
                if (last) {
                    outHx[(size_t)(rowb + i) * N + col0] = v0;
                    outHx[(size_t)(rowb + i) * N + col1] = v1;
                } else {
                    stg2_dev(nxt + (size_t)(rowb + i) * N + col0, (unsigned)f2b(v0));
                    stg2_dev(nxt + (size_t)(rowb + i) * N + col1, (unsigned)f2b(v1));
                }
                acc[mt][0][i] = v0;
                acc[mt][1][i] = v1;
            }
        }

        // release: every wave drains its write-through hx stores to the coherence point
        VMEM_DRAIN();
        __syncthreads();                  // all waves drained; LDS frag reads done
        float* sc = (float*)As;           // reuse As as scratch
        #pragma unroll
        for (int mt = 0; mt < 2; mt++)
            #pragma unroll
            for (int i = 0; i < 4; i++) {
                float v = acc[mt][0][i] * wa0 + acc[mt][1][i] * wa1;
                v += __shfl_xor(v, 1);
                v += __shfl_xor(v, 2);
                v += __shfl_xor(v, 4);
                v += __shfl_xor(v, 8);
                if (r == 0) sc[wn * 64 + wm * 32 + mt * 16 + q * 4 + i] = v;
            }
        __syncthreads();
        if (tid < 64) {
            float v = sc[tid] + sc[64 + tid];
            atomicAdd(&logits[(size_t)s * B_DIM + m0 + tid], v);
        }

        if (!last) {
            // ---- group barrier: arrive + poll (monotonic counter, no fences) ----
            if (tid == 0) {
                __hip_atomic_fetch_add(cnt, 1u, __ATOMIC_RELAXED, __HIP_MEMORY_SCOPE_AGENT);
                const unsigned tgt = 16u * (unsigned)(s + 1);
                while (__hip_atomic_load(cnt, __ATOMIC_RELAXED, __HIP_MEMORY_SCOPE_AGENT) < tgt)
                    __builtin_amdgcn_s_sleep(2);
            }
            __syncthreads();
            const u16* t = cur; cur = nxt; nxt = (u16*)t;
        }
    }
}

// Wsum = bf16(W_ih+W_hh), Whhb = bf16(W_hh), Wihb = bf16(W_ih); bsum = b_ih + b_hh
__global__ void prep_w(const float* __restrict__ Wih, const float* __restrict__ Whh,
                       u16* __restrict__ Wsum, u16* __restrict__ Whhb, u16* __restrict__ Wihb,
                       const float* __restrict__ bih, const float* __restrict__ bhh,
                       float* __restrict__ bsum, int n) {
    int i = blockIdx.x * 256 + threadIdx.x;
    if (i < n) {
        float a = Wih[i], b = Whh[i];
        Wsum[i] = f2b(a + b);
        Whhb[i] = f2b(b);
        Wihb[i] = f2b(a);
    }
    if (i < H_DIM) bsum[i] = bih[i] + bhh[i];
}

__global__ void sigmoid_kernel(const float* __restrict__ logits, const float* __restrict__ b_act,
                               float* __restrict__ out, int n) {
    int i = blockIdx.x * 256 + threadIdx.x;
    if (i < n) {
        float zv = logits[i] + b_act[0];
        out[i] = 1.0f / (1.0f + __expf(-zv));
    }
}

extern "C" void kernel_launch(void* const* d_in, const int* in_sizes, int n_in,
                              void* d_out, int out_size, void* d_ws, size_t ws_size,
                              hipStream_t stream) {
    (void)in_sizes; (void)n_in; (void)out_size; (void)ws_size;
    const int Bn = B_DIM, F = F_DIM, H = H_DIM;

    const float* xin[3] = {(const float*)d_in[0], (const float*)d_in[1], (const float*)d_in[2]};
    const float* W1[3]  = {(const float*)d_in[3], (const float*)d_in[7], (const float*)d_in[11]};
    const float* b1[3]  = {(const float*)d_in[4], (const float*)d_in[8], (const float*)d_in[12]};
    const float* W2[3]  = {(const float*)d_in[5], (const float*)d_in[9], (const float*)d_in[13]};
    const float* b2[3]  = {(const float*)d_in[6], (const float*)d_in[10], (const float*)d_in[14]};
    const float* W_ih   = (const float*)d_in[15];
    const float* W_hh   = (const float*)d_in[16];
    const float* b_ih   = (const float*)d_in[17];
    const float* b_hh   = (const float*)d_in[18];
    const float* W_act  = (const float*)d_in[19];
    const float* b_act  = (const float*)d_in[20];

    // ws layout (phased overlaps; peak ~47 MB)
    const size_t MB = 1024 * 1024;
    char* ws = (char*)d_ws;
    u16*   xl     = (u16*)(ws + 0 * MB);
    u16*   xm     = (u16*)(ws + 4 * MB);
    u16*   xh     = (u16*)(ws + 8 * MB);    // hx ping
    u16*   hxB    = (u16*)(ws + 12 * MB);   // hx pong
    u16*   Wsum   = (u16*)(ws + 16 * MB);
    u16*   Whhb   = (u16*)(ws + 18 * MB);
    u16*   Wihb   = (u16*)(ws + 20 * MB);
    u16*   h1a    = (u16*)(ws + 22 * MB);   // live fc1 -> fc2
    u16*   h1b    = (u16*)(ws + 26 * MB);
    u16*   h1c    = (u16*)(ws + 30 * MB);
    float* pre_xh = (float*)(ws + 22 * MB); // written after fc2 (h1 dead)
    float* pre_xm = (float*)(ws + 30 * MB); // overlaps h1c (dead by then)
    float* pre_xl = (float*)(ws + 38 * MB);
    float* logits = (float*)(ws + 46 * MB);                        // 512 KB
    float* bsum   = (float*)(ws + 46 * MB + 512 * 1024);           // 4 KB
    unsigned* gsync = (unsigned*)(ws + 46 * MB + 516 * 1024);      // 4 KB (32 groups x 128 B)

    dim3 blk(256);
    dim3 grid3(16, 32, 3);

    (void)hipMemsetAsync(logits, 0, (size_t)NSTEP * Bn * sizeof(float), stream);
    (void)hipMemsetAsync(gsync, 0, 4096, stream);
    prep_w<<<dim3((H * H + 255) / 256), blk, 0, stream>>>(W_ih, W_hh, Wsum, Whhb, Wihb,
                                                          b_ih, b_hh, bsum, H * H);

    // fc1: all three branches in ONE z=3 launch; fp32 operands converted in-kernel
    u16* h1[3] = {h1a, h1b, h1c};
    gemm64<1,1,1,0><<<grid3, blk, 0, stream>>>(
        xin[0], xin[1], xin[2], W1[0], W1[1], W1[2], b1[0], b1[1], b1[2],
        h1[0], h1[1], h1[2], H, F);
    // fc2: batched, W2 fp32 converted in-kernel
    gemm64<0,1,1,0><<<grid3, blk, 0, stream>>>(
        h1a, h1b, h1c, W2[0], W2[1], W2[2], b2[0], b2[1], b2[2],
        xl, xm, xh, H, H);
    // pre (batched): pre_* = {xh,xm,xl} @ W_ih^T + b_ih (fp32 out)
    gemm64<0,0,0,1><<<grid3, blk, 0, stream>>>(
        xh, xm, xl, Wihb, Wihb, Wihb, b_ih, b_ih, b_ih,
        pre_xh, pre_xm, pre_xl, H, H);

    // persistent RNN: one plain launch (512 blocks == exact device capacity at 64 KiB LDS)
    float* outHx = (float*)d_out + (size_t)NSTEP * Bn;
    rnn_persist<<<dim3(512), dim3(256), 0, stream>>>(
        xh, hxB, Wsum, Whhb, bsum, b_hh, pre_xh, pre_xm, pre_xl,
        W_act, logits, outHx, gsync);

    sigmoid_kernel<<<dim3((NSTEP * Bn + 255) / 256), blk, 0, stream>>>(
        logits, b_act, (float*)d_out, NSTEP * Bn);
}

// Round 7
// 1188.333 us; speedup vs baseline: 4.8693x; 1.1258x over previous
//
#include <hip/hip_runtime.h>
#include <hip/hip_bf16.h>

typedef unsigned short u16;
typedef short bf16x8 __attribute__((ext_vector_type(8)));   // 8 bf16 (4 VGPRs) MFMA frag
typedef float floatx4 __attribute__((ext_vector_type(4)));  // MFMA acc
typedef int   intx4  __attribute__((ext_vector_type(4)));   // 16B asm payload (true vec type)

#define B_DIM 2048
#define F_DIM 4096
#define H_DIM 1024
#define NSTEP 64

__device__ __forceinline__ float fast_tanh(float x) {
    return 1.0f - 2.0f / (__expf(2.0f * x) + 1.0f);
}

// fp32 -> bf16 RNE via compiler cast (emits v_cvt_pk_bf16_f32 for pairs)
__device__ __forceinline__ u16 f2b(float x) {
    union { __hip_bfloat16 b; u16 u; } v;
    v.b = __float2bfloat16(x);
    return v.u;
}

// ---- device-scope (cross-XCD-coherent) memory ops: bypass L1/L2, hit the memory-side
// Infinity Cache (the device coherence point). No wbl2/inv cache-maintenance needed.
__device__ __forceinline__ void ldg16_dev(int4& d, const void* p) {
    asm volatile("global_load_dwordx4 %0, %1, off sc0 sc1" : "=v"(d) : "v"(p));
}
__device__ __forceinline__ void ldg16(int4& d, const void* p) {
    asm volatile("global_load_dwordx4 %0, %1, off" : "=v"(d) : "v"(p));
}
__device__ __forceinline__ void stg16_dev(void* p, intx4 v) {   // intx4: clang vec type,
    asm volatile("global_store_dwordx4 %0, %1, off sc0 sc1"     // struct int4 inputs are
                 :: "v"(p), "v"(v) : "memory");                 // rejected by clang asm
}
// wait for ALL outstanding vmem; sched_barrier pins it (rule #18)
#define VMEM_DRAIN() do { asm volatile("s_waitcnt vmcnt(0)" ::: "memory"); \
                          __builtin_amdgcn_sched_barrier(0); } while (0)

template<int F32>
__device__ __forceinline__ int4 ld8(const void* base, size_t elemOff) {
    if constexpr (F32) {
        const float* p = (const float*)base + elemOff;
        float4 lo = *(const float4*)p;
        float4 hi = *(const float4*)(p + 4);
        union { u16 h[8]; int4 v; } rr;
        rr.h[0] = f2b(lo.x); rr.h[1] = f2b(lo.y); rr.h[2] = f2b(lo.z); rr.h[3] = f2b(lo.w);
        rr.h[4] = f2b(hi.x); rr.h[5] = f2b(hi.y); rr.h[6] = f2b(hi.z); rr.h[7] = f2b(hi.w);
        return rr.v;
    } else {
        return *(const int4*)((const u16*)base + elemOff);
    }
}

// ---------------- batched/selector GEMM for the parallel (MLP/pre) phase ----------------
// C[z] = act(A[z] @ W[z]^T + bias1[z]); grid must be (16, 32, z). BM=BN=BK=64, 256 thr.
template<int AF32, int WF32, int ACT, int OUT_F32>
__global__ __launch_bounds__(256)
void gemm64(const void* __restrict__ A0, const void* __restrict__ A1, const void* __restrict__ A2,
            const void* __restrict__ Wp0, const void* __restrict__ Wp1, const void* __restrict__ Wp2,
            const float* __restrict__ bia0, const float* __restrict__ bia1, const float* __restrict__ bia2,
            void* __restrict__ C0, void* __restrict__ C1, void* __restrict__ C2,
            const int N, const int K)
{
    constexpr int BM = 64, BN = 64, BK = 64, LS = 72;
    __shared__ u16 As[2][BM * LS];
    __shared__ u16 Bs[2][BN * LS];

    const int z = blockIdx.z;
    const void*  A     = (z == 0) ? A0 : (z == 1) ? A1 : A2;
    const void*  W     = (z == 0) ? Wp0 : (z == 1) ? Wp1 : Wp2;
    const float* bias1 = (z == 0) ? bia0 : (z == 1) ? bia1 : bia2;
    void*        Cout  = (z == 0) ? C0 : (z == 1) ? C1 : C2;

    const int tid  = threadIdx.x;
    const int wave = tid >> 6, lane = tid & 63;
    const int wm = wave >> 1, wn = wave & 1;
    const int r = lane & 15, q = lane >> 4;

    const int lin = blockIdx.y * 16 + blockIdx.x;
    const int mti = (lin & 7) | ((lin >> 7) << 3);
    const int nti = (lin >> 3) & 15;
    const int m0 = mti * BM, n0 = nti * BN;

    floatx4 acc[2][2];
    const floatx4 zf = {0.f, 0.f, 0.f, 0.f};
    #pragma unroll
    for (int a = 0; a < 2; a++)
        #pragma unroll
        for (int b = 0; b < 2; b++) acc[a][b] = zf;

    const int row0 = tid >> 3, kc = (tid & 7) << 3, row1 = row0 + 32;
    const size_t aOff0 = (size_t)(m0 + row0) * K + kc;
    const size_t aOff1 = (size_t)(m0 + row1) * K + kc;
    const size_t wOff0 = (size_t)(n0 + row0) * K + kc;
    const size_t wOff1 = (size_t)(n0 + row1) * K + kc;

    int4 av0 = ld8<AF32>(A, aOff0);
    int4 av1 = ld8<AF32>(A, aOff1);
    int4 bv0 = ld8<WF32>(W, wOff0);
    int4 bv1 = ld8<WF32>(W, wOff1);

    int p = 0;
    for (int kb = 0; kb < K; kb += BK) {
        *(int4*)&As[p][row0 * LS + kc] = av0;
        *(int4*)&As[p][row1 * LS + kc] = av1;
        *(int4*)&Bs[p][row0 * LS + kc] = bv0;
        *(int4*)&Bs[p][row1 * LS + kc] = bv1;
        __syncthreads();
        if (kb + BK < K) {
            av0 = ld8<AF32>(A, aOff0 + kb + BK);
            av1 = ld8<AF32>(A, aOff1 + kb + BK);
            bv0 = ld8<WF32>(W, wOff0 + kb + BK);
            bv1 = ld8<WF32>(W, wOff1 + kb + BK);
        }
        bf16x8 af[2][2], bfr[2][2];
        #pragma unroll
        for (int ks = 0; ks < 2; ks++)
            #pragma unroll
            for (int t = 0; t < 2; t++) {
                af[ks][t]  = *(const bf16x8*)&As[p][(wm * 32 + t * 16 + r) * LS + ks * 32 + q * 8];
                bfr[ks][t] = *(const bf16x8*)&Bs[p][(wn * 32 + t * 16 + r) * LS + ks * 32 + q * 8];
            }
        #pragma unroll
        for (int ks = 0; ks < 2; ks++)
            #pragma unroll
            for (int mt = 0; mt < 2; mt++)
                #pragma unroll
                for (int nt = 0; nt < 2; nt++)
                    acc[mt][nt] = __builtin_amdgcn_mfma_f32_16x16x32_bf16(af[ks][mt], bfr[ks][nt], acc[mt][nt], 0, 0, 0);
        p ^= 1;
    }

    #pragma unroll
    for (int mt = 0; mt < 2; mt++)
        #pragma unroll
        for (int nt = 0; nt < 2; nt++) {
            const int col  = n0 + wn * 32 + nt * 16 + r;
            const int rowb = m0 + wm * 32 + mt * 16 + q * 4;
            const float bb = bias1 ? bias1[col] : 0.f;
            #pragma unroll
            for (int i = 0; i < 4; i++) {
                float v = acc[mt][nt][i] + bb;
                if (ACT == 1) v = fmaxf(v, 0.f);
                if (OUT_F32) ((float*)Cout)[(size_t)(rowb + i) * N + col] = v;
                else ((u16*)Cout)[(size_t)(rowb + i) * N + col] = f2b(v);
            }
        }
}

// ---------------- persistent RNN: all 64 steps in ONE launch ----------------
// Grid 512 blocks x 256 thr; 64 KiB LDS -> exactly 2 blocks/CU x 256 CU = 512 co-resident.
// hx coherence: device-scope write-through dwordx4 stores (sc0 sc1 -> Infinity Cache) and
// device-scope loads; zero cache-maintenance ops. Per-group (16 blocks sharing mti)
// monotonic atomic barrier.
// 2-deep prefetch with counted vmcnt(8) (loop fully unrolled -> compile-time waits; no
// compiler VMEM inside the K-loop), LDS-staged coalesced hx output (512 dwordx4/block
// instead of 4096 2-byte stores), arrive-before-atomics.
__global__ __launch_bounds__(256, 2)
void rnn_persist(u16* __restrict__ bufA, u16* __restrict__ bufB,
                 const u16* __restrict__ Wsum, const u16* __restrict__ Whhb,
                 const float* __restrict__ bsum, const float* __restrict__ bhh,
                 const float* __restrict__ pre_xh, const float* __restrict__ pre_xm,
                 const float* __restrict__ pre_xl,
                 const float* __restrict__ Wact, float* __restrict__ logits,
                 float* __restrict__ outHx, unsigned* __restrict__ gsync)
{
    constexpr int BM = 64, BN = 64, BK = 128, K = H_DIM, N = H_DIM, NITER = K / BK; // 8
    __shared__ u16 As[2][BM * BK];   // 32 KiB
    __shared__ u16 Bs[2][BN * BK];   // 32 KiB

    const int tid  = threadIdx.x;
    const int wave = tid >> 6, lane = tid & 63;
    const int wm = wave >> 1, wn = wave & 1;
    const int r = lane & 15, q = lane >> 4;

    const int lin = blockIdx.x;
    const int mti = (lin & 7) | ((lin >> 7) << 3);   // group: 16 blocks share mti
    const int nti = (lin >> 3) & 15;
    const int m0 = mti * BM, n0 = nti * BN;

    // staging: 64 rows x 128 cols; 4 threads/row, 4 x 16B chunks, XOR-swizzled LDS
    const int row = tid >> 2, c = tid & 3;
    const size_t aOff = (size_t)(m0 + row) * K + c * 8;
    const size_t wOff = (size_t)(n0 + row) * K + c * 8;
    int dst[4];
    #pragma unroll
    for (int j = 0; j < 4; j++)
        dst[j] = row * BK + (((c * 8) + j * 32) ^ ((row & 7) * 8));
    const int sw = (r & 7) * 8;

    unsigned* cnt = gsync + mti * 32;   // 128-B padded counter per group

    const u16* cur = bufA;
    u16* nxt = bufB;

    for (int s = 0; s < NSTEP; ++s) {
        const u16* W; const float* bias; const float* pre = nullptr;
        if (s == 15)                 { W = Whhb; bias = bhh; pre = pre_xh; }
        else if (s == 21 || s == 37) { W = Whhb; bias = bhh; pre = pre_xm; }
        else if (s == 42 || s == 58) { W = Whhb; bias = bhh; pre = pre_xl; }
        else                         { W = Wsum; bias = bsum; }
        const bool last = (s == NSTEP - 1);

        floatx4 acc[2][2];
        const floatx4 zf = {0.f, 0.f, 0.f, 0.f};
        acc[0][0] = zf; acc[0][1] = zf; acc[1][0] = zf; acc[1][1] = zf;

        // 2-deep prefetch: two register sets; FIFO order = oldest first
        int4 av0[4], bv0[4], av1[4], bv1[4];
        #pragma unroll
        for (int j = 0; j < 4; j++) {
            ldg16_dev(av0[j], cur + aOff + j * 32);
            ldg16(bv0[j], W + wOff + j * 32);
        }
        #pragma unroll
        for (int j = 0; j < 4; j++) {
            ldg16_dev(av1[j], cur + aOff + BK + j * 32);
            ldg16(bv1[j], W + wOff + BK + j * 32);
        }

        int p = 0;
        #pragma unroll
        for (int it = 0; it < NITER; ++it) {
            // wait for THIS iter's 8 loads (oldest); 8 newer (next iter's) stay in flight
            if (it < NITER - 1) { asm volatile("s_waitcnt vmcnt(8)" ::: "memory"); }
            else                { asm volatile("s_waitcnt vmcnt(0)" ::: "memory"); }
            __builtin_amdgcn_sched_barrier(0);
            int4 (&av)[4] = (it & 1) ? av1 : av0;
            int4 (&bv)[4] = (it & 1) ? bv1 : bv0;
            #pragma unroll
            for (int j = 0; j < 4; j++) {
                *(int4*)&As[p][dst[j]] = av[j];
                *(int4*)&Bs[p][dst[j]] = bv[j];
            }
            __syncthreads();
            if (it + 2 < NITER) {
                const int kb2 = (it + 2) * BK;
                #pragma unroll
                for (int j = 0; j < 4; j++) {
                    ldg16_dev(av[j], cur + aOff + kb2 + j * 32);
                    ldg16(bv[j], W + wOff + kb2 + j * 32);
                }
            }
            #pragma unroll
            for (int ks = 0; ks < 4; ks++) {
                const int cb = ((ks * 32) + q * 8) ^ sw;
                bf16x8 a0 = *(const bf16x8*)&As[p][(wm * 32 +      r) * BK + cb];
                bf16x8 a1 = *(const bf16x8*)&As[p][(wm * 32 + 16 + r) * BK + cb];
                bf16x8 b0 = *(const bf16x8*)&Bs[p][(wn * 32 +      r) * BK + cb];
                bf16x8 b1 = *(const bf16x8*)&Bs[p][(wn * 32 + 16 + r) * BK + cb];
                acc[0][0] = __builtin_amdgcn_mfma_f32_16x16x32_bf16(a0, b0, acc[0][0], 0, 0, 0);
                acc[0][1] = __builtin_amdgcn_mfma_f32_16x16x32_bf16(a0, b1, acc[0][1], 0, 0, 0);
                acc[1][0] = __builtin_amdgcn_mfma_f32_16x16x32_bf16(a1, b0, acc[1][0], 0, 0, 0);
                acc[1][1] = __builtin_amdgcn_mfma_f32_16x16x32_bf16(a1, b1, acc[1][1], 0, 0, 0);
            }
            p ^= 1;
        }

        // ---- epilogue: tanh in registers. C/D layout: row = q*4+i, col = r. ----
        const int col0 = n0 + wn * 32 + r;
        const int col1 = col0 + 16;
        const float bb0 = bias[col0], bb1 = bias[col1];
        const float wa0 = Wact[col0], wa1 = Wact[col1];
        float fv0[2][4], fv1[2][4];
        #pragma unroll
        for (int mt = 0; mt < 2; mt++) {
            const int rowb = m0 + wm * 32 + mt * 16 + q * 4;
            #pragma unroll
            for (int i = 0; i < 4; i++) {
                float v0 = acc[mt][0][i] + bb0;
                float v1 = acc[mt][1][i] + bb1;
                if (pre) {
                    v0 += pre[(size_t)(rowb + i) * N + col0];
                    v1 += pre[(size_t)(rowb + i) * N + col1];
                }
                fv0[mt][i] = fast_tanh(v0);
                fv1[mt][i] = fast_tanh(v1);
            }
        }
        if (last) {
            #pragma unroll
            for (int mt = 0; mt < 2; mt++) {
                const int rowb = m0 + wm * 32 + mt * 16 + q * 4;
                #pragma unroll
                for (int i = 0; i < 4; i++) {
                    outHx[(size_t)(rowb + i) * N + col0] = fv0[mt][i];
                    outHx[(size_t)(rowb + i) * N + col1] = fv1[mt][i];
                }
            }
        }

        __syncthreads();                  // all waves' MFMA LDS reads done; reuse As
        u16*   Cs = (u16*)As;             // 64x64 bf16 = 8 KB staging for coalesced store
        float* sc = (float*)((char*)As + 8192);   // actor scratch (2 x 64 floats)
        if (!last) {
            #pragma unroll
            for (int mt = 0; mt < 2; mt++) {
                const int rl = wm * 32 + mt * 16 + q * 4;
                #pragma unroll
                for (int i = 0; i < 4; i++) {
                    Cs[(rl + i) * 64 + wn * 32 + r]      = f2b(fv0[mt][i]);
                    Cs[(rl + i) * 64 + wn * 32 + 16 + r] = f2b(fv1[mt][i]);
                }
            }
        }
        // actor head partials: shuffle-reduce 32 cols -> sc
        #pragma unroll
        for (int mt = 0; mt < 2; mt++)
            #pragma unroll
            for (int i = 0; i < 4; i++) {
                float v = fv0[mt][i] * wa0 + fv1[mt][i] * wa1;
                v += __shfl_xor(v, 1);
                v += __shfl_xor(v, 2);
                v += __shfl_xor(v, 4);
                v += __shfl_xor(v, 8);
                if (r == 0) sc[wn * 64 + wm * 32 + mt * 16 + q * 4 + i] = v;
            }
        __syncthreads();

        if (!last) {
            // coalesced hx store: 512 x dwordx4 per block (2 per thread)
            #pragma unroll
            for (int u2 = 0; u2 < 2; u2++) {
                const int ch = tid + u2 * 256;
                const int rw = ch >> 3, cc = ch & 7;
                intx4 val = *(const intx4*)&Cs[rw * 64 + cc * 8];
                stg16_dev(nxt + (size_t)(m0 + rw) * N + n0 + cc * 8, val);
            }
            VMEM_DRAIN();                 // hx stores at coherence point
            if (tid == 0)                 // arrive FIRST (peers can progress)...
                __hip_atomic_fetch_add(cnt, 1u, __ATOMIC_RELAXED, __HIP_MEMORY_SCOPE_AGENT);
        }
        if (tid < 64) {                   // ...then logits atomics (off the critical path)
            float v = sc[tid] + sc[64 + tid];
            atomicAdd(&logits[(size_t)s * B_DIM + m0 + tid], v);
        }
        if (!last) {
            VMEM_DRAIN();                 // atomics drained so counted waits stay exact
            if (tid == 0) {
                const unsigned tgt = 16u * (unsigned)(s + 1);
                while (__hip_atomic_load(cnt, __ATOMIC_RELAXED, __HIP_MEMORY_SCOPE_AGENT) < tgt)
                    __builtin_amdgcn_s_sleep(2);
            }
            __syncthreads();
            const u16* t = cur; cur = nxt; nxt = (u16*)t;
        }
    }
}

// fp32 -> bf16 bulk convert, z selects tensor
__global__ void convert_bf16(const float* __restrict__ s0, const float* __restrict__ s1,
                             const float* __restrict__ s2,
                             u16* __restrict__ d0, u16* __restrict__ d1, u16* __restrict__ d2,
                             int n)
{
    const int z = blockIdx.z;
    const float* s = (z == 0) ? s0 : (z == 1) ? s1 : s2;
    u16* d = (z == 0) ? d0 : (z == 1) ? d1 : d2;
    int i = (blockIdx.x * 256 + threadIdx.x) * 8;
    if (i < n) {
        float4 lo = *(const float4*)(s + i);
        float4 hi = *(const float4*)(s + i + 4);
        union { u16 h[8]; int4 v; } rr;
        rr.h[0] = f2b(lo.x); rr.h[1] = f2b(lo.y); rr.h[2] = f2b(lo.z); rr.h[3] = f2b(lo.w);
        rr.h[4] = f2b(hi.x); rr.h[5] = f2b(hi.y); rr.h[6] = f2b(hi.z); rr.h[7] = f2b(hi.w);
        *(int4*)(d + i) = rr.v;
    }
}

// Wsum = bf16(W_ih+W_hh), Whhb = bf16(W_hh), Wihb = bf16(W_ih); bsum = b_ih + b_hh
__global__ void prep_w(const float* __restrict__ Wih, const float* __restrict__ Whh,
                       u16* __restrict__ Wsum, u16* __restrict__ Whhb, u16* __restrict__ Wihb,
                       const float* __restrict__ bih, const float* __restrict__ bhh,
                       float* __restrict__ bsum, int n) {
    int i = blockIdx.x * 256 + threadIdx.x;
    if (i < n) {
        float a = Wih[i], b = Whh[i];
        Wsum[i] = f2b(a + b);
        Whhb[i] = f2b(b);
        Wihb[i] = f2b(a);
    }
    if (i < H_DIM) bsum[i] = bih[i] + bhh[i];
}

__global__ void sigmoid_kernel(const float* __restrict__ logits, const float* __restrict__ b_act,
                               float* __restrict__ out, int n) {
    int i = blockIdx.x * 256 + threadIdx.x;
    if (i < n) {
        float zv = logits[i] + b_act[0];
        out[i] = 1.0f / (1.0f + __expf(-zv));
    }
}

extern "C" void kernel_launch(void* const* d_in, const int* in_sizes, int n_in,
                              void* d_out, int out_size, void* d_ws, size_t ws_size,
                              hipStream_t stream) {
    (void)in_sizes; (void)n_in; (void)out_size;
    const int Bn = B_DIM, F = F_DIM, H = H_DIM;

    const float* xin[3] = {(const float*)d_in[0], (const float*)d_in[1], (const float*)d_in[2]};
    const float* W1[3]  = {(const float*)d_in[3], (const float*)d_in[7], (const float*)d_in[11]};
    const float* b1[3]  = {(const float*)d_in[4], (const float*)d_in[8], (const float*)d_in[12]};
    const float* W2[3]  = {(const float*)d_in[5], (const float*)d_in[9], (const float*)d_in[13]};
    const float* b2[3]  = {(const float*)d_in[6], (const float*)d_in[10], (const float*)d_in[14]};
    const float* W_ih   = (const float*)d_in[15];
    const float* W_hh   = (const float*)d_in[16];
    const float* b_ih   = (const float*)d_in[17];
    const float* b_hh   = (const float*)d_in[18];
    const float* W_act  = (const float*)d_in[19];
    const float* b_act  = (const float*)d_in[20];

    // ws layout (phased overlaps; base ~47 MB; optional bf16 pre-convert region above)
    const size_t MB = 1024 * 1024;
    char* ws = (char*)d_ws;
    u16*   xl     = (u16*)(ws + 0 * MB);
    u16*   xm     = (u16*)(ws + 4 * MB);
    u16*   xh     = (u16*)(ws + 8 * MB);    // hx ping
    u16*   hxB    = (u16*)(ws + 12 * MB);   // hx pong
    u16*   Wsum   = (u16*)(ws + 16 * MB);
    u16*   Whhb   = (u16*)(ws + 18 * MB);
    u16*   Wihb   = (u16*)(ws + 20 * MB);
    u16*   h1a    = (u16*)(ws + 22 * MB);   // live fc1 -> fc2
    u16*   h1b    = (u16*)(ws + 26 * MB);
    u16*   h1c    = (u16*)(ws + 30 * MB);
    float* pre_xh = (float*)(ws + 22 * MB); // written after fc2 (h1 dead)
    float* pre_xm = (float*)(ws + 30 * MB); // overlaps h1c (dead by then)
    float* pre_xl = (float*)(ws + 38 * MB);
    float* logits = (float*)(ws + 46 * MB);                        // 512 KB
    float* bsum   = (float*)(ws + 46 * MB + 512 * 1024);           // 4 KB
    unsigned* gsync = (unsigned*)(ws + 46 * MB + 516 * 1024);      // 4 KB (32 groups x 128 B)
    // optional bf16 pre-convert region (only if ws is big enough):
    u16* xb[3]  = {(u16*)(ws + 48 * MB), (u16*)(ws + 64 * MB), (u16*)(ws + 80 * MB)};   // 16 MB each
    u16* W1b[3] = {(u16*)(ws + 96 * MB), (u16*)(ws + 104 * MB), (u16*)(ws + 112 * MB)}; //  8 MB each
    u16* W2b[3] = {(u16*)(ws + 120 * MB), (u16*)(ws + 122 * MB), (u16*)(ws + 124 * MB)};//  2 MB each
    const bool big = ws_size >= (size_t)126 * MB;

    dim3 blk(256);
    dim3 grid3(16, 32, 3);

    (void)hipMemsetAsync(logits, 0, (size_t)NSTEP * Bn * sizeof(float), stream);
    (void)hipMemsetAsync(gsync, 0, 4096, stream);
    prep_w<<<dim3((H * H + 255) / 256), blk, 0, stream>>>(W_ih, W_hh, Wsum, Whhb, Wihb,
                                                          b_ih, b_hh, bsum, H * H);

    u16* h1[3] = {h1a, h1b, h1c};
    if (big) {
        // pre-convert x, W1, W2 to bf16 -> fc1/fc2 run the pure-bf16 staging path
        const int nX = Bn * F, nW1 = H * F, nW2 = H * H;
        convert_bf16<<<dim3((nX / 8 + 255) / 256, 1, 3), blk, 0, stream>>>(
            xin[0], xin[1], xin[2], xb[0], xb[1], xb[2], nX);
        convert_bf16<<<dim3((nW1 / 8 + 255) / 256, 1, 3), blk, 0, stream>>>(
            W1[0], W1[1], W1[2], W1b[0], W1b[1], W1b[2], nW1);
        convert_bf16<<<dim3((nW2 / 8 + 255) / 256, 1, 3), blk, 0, stream>>>(
            W2[0], W2[1], W2[2], W2b[0], W2b[1], W2b[2], nW2);
        gemm64<0,0,1,0><<<grid3, blk, 0, stream>>>(
            xb[0], xb[1], xb[2], W1b[0], W1b[1], W1b[2], b1[0], b1[1], b1[2],
            h1[0], h1[1], h1[2], H, F);
        gemm64<0,0,1,0><<<grid3, blk, 0, stream>>>(
            h1a, h1b, h1c, W2b[0], W2b[1], W2b[2], b2[0], b2[1], b2[2],
            xl, xm, xh, H, H);
    } else {
        // fallback: fp32 operands converted in-kernel (round-5 path)
        gemm64<1,1,1,0><<<grid3, blk, 0, stream>>>(
            xin[0], xin[1], xin[2], W1[0], W1[1], W1[2], b1[0], b1[1], b1[2],
            h1[0], h1[1], h1[2], H, F);
        gemm64<0,1,1,0><<<grid3, blk, 0, stream>>>(
            h1a, h1b, h1c, W2[0], W2[1], W2[2], b2[0], b2[1], b2[2],
            xl, xm, xh, H, H);
    }
    // pre (batched): pre_* = {xh,xm,xl} @ W_ih^T + b_ih (fp32 out)
    gemm64<0,0,0,1><<<grid3, blk, 0, stream>>>(
        xh, xm, xl, Wihb, Wihb, Wihb, b_ih, b_ih, b_ih,
        pre_xh, pre_xm, pre_xl, H, H);

    // persistent RNN: one plain launch (512 blocks == exact device capacity at 64 KiB LDS)
    float* outHx = (float*)d_out + (size_t)NSTEP * Bn;
    rnn_persist<<<dim3(512), dim3(256), 0, stream>>>(
        xh, hxB, Wsum, Whhb, bsum, b_hh, pre_xh, pre_xm, pre_xl,
        W_act, logits, outHx, gsync);

    sigmoid_kernel<<<dim3((NSTEP * Bn + 255) / 256), blk, 0, stream>>>(
        logits, b_act, (float*)d_out, NSTEP * Bn);
}

// Round 8
// 1174.068 us; speedup vs baseline: 4.9284x; 1.0122x over previous
//
#include <hip/hip_runtime.h>
#include <hip/hip_bf16.h>

typedef unsigned short u16;
typedef short bf16x8 __attribute__((ext_vector_type(8)));   // 8 bf16 (4 VGPRs) MFMA frag
typedef float floatx4 __attribute__((ext_vector_type(4)));  // MFMA acc
typedef int   intx4  __attribute__((ext_vector_type(4)));   // 16B asm payload (true vec type)

#define B_DIM 2048
#define F_DIM 4096
#define H_DIM 1024
#define NSTEP 64

__device__ __forceinline__ float fast_tanh(float x) {
    return 1.0f - 2.0f / (__expf(2.0f * x) + 1.0f);
}

// fp32 -> bf16 RNE via compiler cast (emits v_cvt_pk_bf16_f32 for pairs)
__device__ __forceinline__ u16 f2b(float x) {
    union { __hip_bfloat16 b; u16 u; } v;
    v.b = __float2bfloat16(x);
    return v.u;
}

// ---- device-scope (cross-XCD-coherent) memory ops: bypass L1/L2, hit the memory-side
// Infinity Cache (the device coherence point). No wbl2/inv cache-maintenance needed.
__device__ __forceinline__ void ldg16_dev(int4& d, const void* p) {
    asm volatile("global_load_dwordx4 %0, %1, off sc0 sc1" : "=v"(d) : "v"(p));
}
__device__ __forceinline__ void ldg16(int4& d, const void* p) {
    asm volatile("global_load_dwordx4 %0, %1, off" : "=v"(d) : "v"(p));
}
__device__ __forceinline__ void stg16_dev(void* p, intx4 v) {   // intx4: clang vec type,
    asm volatile("global_store_dwordx4 %0, %1, off sc0 sc1"     // struct int4 inputs are
                 :: "v"(p), "v"(v) : "memory");                 // rejected by clang asm
}
// wait for ALL outstanding vmem; sched_barrier pins it (rule #18)
#define VMEM_DRAIN() do { asm volatile("s_waitcnt vmcnt(0)" ::: "memory"); \
                          __builtin_amdgcn_sched_barrier(0); } while (0)

template<int F32>
__device__ __forceinline__ int4 ld8(const void* base, size_t elemOff) {
    if constexpr (F32) {
        const float* p = (const float*)base + elemOff;
        float4 lo = *(const float4*)p;
        float4 hi = *(const float4*)(p + 4);
        union { u16 h[8]; int4 v; } rr;
        rr.h[0] = f2b(lo.x); rr.h[1] = f2b(lo.y); rr.h[2] = f2b(lo.z); rr.h[3] = f2b(lo.w);
        rr.h[4] = f2b(hi.x); rr.h[5] = f2b(hi.y); rr.h[6] = f2b(hi.z); rr.h[7] = f2b(hi.w);
        return rr.v;
    } else {
        return *(const int4*)((const u16*)base + elemOff);
    }
}

// ---------------- batched/selector GEMM for the parallel (MLP/pre) phase ----------------
// C[z] = act(A[z] @ W[z]^T + bias1[z]); grid must be (16, 32, z). BM=BN=BK=64, 256 thr.
template<int AF32, int WF32, int ACT, int OUT_F32>
__global__ __launch_bounds__(256)
void gemm64(const void* __restrict__ A0, const void* __restrict__ A1, const void* __restrict__ A2,
            const void* __restrict__ Wp0, const void* __restrict__ Wp1, const void* __restrict__ Wp2,
            const float* __restrict__ bia0, const float* __restrict__ bia1, const float* __restrict__ bia2,
            void* __restrict__ C0, void* __restrict__ C1, void* __restrict__ C2,
            const int N, const int K)
{
    constexpr int BM = 64, BN = 64, BK = 64, LS = 72;
    __shared__ u16 As[2][BM * LS];
    __shared__ u16 Bs[2][BN * LS];

    const int z = blockIdx.z;
    const void*  A     = (z == 0) ? A0 : (z == 1) ? A1 : A2;
    const void*  W     = (z == 0) ? Wp0 : (z == 1) ? Wp1 : Wp2;
    const float* bias1 = (z == 0) ? bia0 : (z == 1) ? bia1 : bia2;
    void*        Cout  = (z == 0) ? C0 : (z == 1) ? C1 : C2;

    const int tid  = threadIdx.x;
    const int wave = tid >> 6, lane = tid & 63;
    const int wm = wave >> 1, wn = wave & 1;
    const int r = lane & 15, q = lane >> 4;

    const int lin = blockIdx.y * 16 + blockIdx.x;
    const int mti = (lin & 7) | ((lin >> 7) << 3);
    const int nti = (lin >> 3) & 15;
    const int m0 = mti * BM, n0 = nti * BN;

    floatx4 acc[2][2];
    const floatx4 zf = {0.f, 0.f, 0.f, 0.f};
    #pragma unroll
    for (int a = 0; a < 2; a++)
        #pragma unroll
        for (int b = 0; b < 2; b++) acc[a][b] = zf;

    const int row0 = tid >> 3, kc = (tid & 7) << 3, row1 = row0 + 32;
    const size_t aOff0 = (size_t)(m0 + row0) * K + kc;
    const size_t aOff1 = (size_t)(m0 + row1) * K + kc;
    const size_t wOff0 = (size_t)(n0 + row0) * K + kc;
    const size_t wOff1 = (size_t)(n0 + row1) * K + kc;

    int4 av0 = ld8<AF32>(A, aOff0);
    int4 av1 = ld8<AF32>(A, aOff1);
    int4 bv0 = ld8<WF32>(W, wOff0);
    int4 bv1 = ld8<WF32>(W, wOff1);

    int p = 0;
    for (int kb = 0; kb < K; kb += BK) {
        *(int4*)&As[p][row0 * LS + kc] = av0;
        *(int4*)&As[p][row1 * LS + kc] = av1;
        *(int4*)&Bs[p][row0 * LS + kc] = bv0;
        *(int4*)&Bs[p][row1 * LS + kc] = bv1;
        __syncthreads();
        if (kb + BK < K) {
            av0 = ld8<AF32>(A, aOff0 + kb + BK);
            av1 = ld8<AF32>(A, aOff1 + kb + BK);
            bv0 = ld8<WF32>(W, wOff0 + kb + BK);
            bv1 = ld8<WF32>(W, wOff1 + kb + BK);
        }
        bf16x8 af[2][2], bfr[2][2];
        #pragma unroll
        for (int ks = 0; ks < 2; ks++)
            #pragma unroll
            for (int t = 0; t < 2; t++) {
                af[ks][t]  = *(const bf16x8*)&As[p][(wm * 32 + t * 16 + r) * LS + ks * 32 + q * 8];
                bfr[ks][t] = *(const bf16x8*)&Bs[p][(wn * 32 + t * 16 + r) * LS + ks * 32 + q * 8];
            }
        #pragma unroll
        for (int ks = 0; ks < 2; ks++)
            #pragma unroll
            for (int mt = 0; mt < 2; mt++)
                #pragma unroll
                for (int nt = 0; nt < 2; nt++)
                    acc[mt][nt] = __builtin_amdgcn_mfma_f32_16x16x32_bf16(af[ks][mt], bfr[ks][nt], acc[mt][nt], 0, 0, 0);
        p ^= 1;
    }

    #pragma unroll
    for (int mt = 0; mt < 2; mt++)
        #pragma unroll
        for (int nt = 0; nt < 2; nt++) {
            const int col  = n0 + wn * 32 + nt * 16 + r;
            const int rowb = m0 + wm * 32 + mt * 16 + q * 4;
            const float bb = bias1 ? bias1[col] : 0.f;
            #pragma unroll
            for (int i = 0; i < 4; i++) {
                float v = acc[mt][nt][i] + bb;
                if (ACT == 1) v = fmaxf(v, 0.f);
                if (OUT_F32) ((float*)Cout)[(size_t)(rowb + i) * N + col] = v;
                else ((u16*)Cout)[(size_t)(rowb + i) * N + col] = f2b(v);
            }
        }
}

// ---------------- persistent RNN: all 64 steps in ONE launch ----------------
// Grid 512 blocks x 256 thr; 64 KiB LDS -> exactly 2 blocks/CU x 256 CU = 512 co-resident.
// hx coherence: device-scope write-through dwordx4 stores + device-scope loads; zero
// cache-maintenance ops. Per-group (16 blocks sharing mti) monotonic atomic barrier.
// LDS swizzle: phys = logical ^ ((row&7)*8) ^ ((row&1)*32)  [elements, bits 3-5].
// The extra (row&1)<<5 term injects row parity into chunk-bit2 so STAGING WRITES are
// 2-way within each 16-lane quarter (rows 0-3 x c 0-3); the old (row&7)*8-only swizzle
// left bit2 = (j&1) row-invariant -> 4-way write conflict = 1.38e8 conflict cycles
// (~25% of round-7 runtime). Reads stay 2-way: r=0..7 -> chunks {0,5,2,7,4,1,6,3}.
__global__ __launch_bounds__(256, 2)
void rnn_persist(u16* __restrict__ bufA, u16* __restrict__ bufB,
                 const u16* __restrict__ Wsum, const u16* __restrict__ Whhb,
                 const float* __restrict__ bsum, const float* __restrict__ bhh,
                 const float* __restrict__ pre_xh, const float* __restrict__ pre_xm,
                 const float* __restrict__ pre_xl,
                 const float* __restrict__ Wact, float* __restrict__ logits,
                 float* __restrict__ outHx, unsigned* __restrict__ gsync)
{
    constexpr int BM = 64, BN = 64, BK = 128, K = H_DIM, N = H_DIM, NITER = K / BK; // 8
    __shared__ u16 As[2][BM * BK];   // 32 KiB
    __shared__ u16 Bs[2][BN * BK];   // 32 KiB

    const int tid  = threadIdx.x;
    const int wave = tid >> 6, lane = tid & 63;
    const int wm = wave >> 1, wn = wave & 1;
    const int r = lane & 15, q = lane >> 4;

    const int lin = blockIdx.x;
    const int mti = (lin & 7) | ((lin >> 7) << 3);   // group: 16 blocks share mti
    const int nti = (lin >> 3) & 15;
    const int m0 = mti * BM, n0 = nti * BN;

    // staging: 64 rows x 128 cols; 4 threads/row, 4 x 16B chunks, XOR-swizzled LDS
    const int row = tid >> 2, c = tid & 3;
    const size_t aOff = (size_t)(m0 + row) * K + c * 8;
    const size_t wOff = (size_t)(n0 + row) * K + c * 8;
    int dst[4];
    #pragma unroll
    for (int j = 0; j < 4; j++)
        dst[j] = row * BK + (((c * 8) + j * 32) ^ ((row & 7) * 8) ^ ((row & 1) * 32));
    const int sw = ((r & 7) * 8) ^ ((r & 1) * 32);   // read-side: same S(row), row ~ r

    unsigned* cnt = gsync + mti * 32;   // 128-B padded counter per group

    const u16* cur = bufA;
    u16* nxt = bufB;

    for (int s = 0; s < NSTEP; ++s) {
        const u16* W; const float* bias; const float* pre = nullptr;
        if (s == 15)                 { W = Whhb; bias = bhh; pre = pre_xh; }
        else if (s == 21 || s == 37) { W = Whhb; bias = bhh; pre = pre_xm; }
        else if (s == 42 || s == 58) { W = Whhb; bias = bhh; pre = pre_xl; }
        else                         { W = Wsum; bias = bsum; }
        const bool last = (s == NSTEP - 1);

        floatx4 acc[2][2];
        const floatx4 zf = {0.f, 0.f, 0.f, 0.f};
        acc[0][0] = zf; acc[0][1] = zf; acc[1][0] = zf; acc[1][1] = zf;

        // 2-deep prefetch: two register sets; FIFO order = oldest first
        int4 av0[4], bv0[4], av1[4], bv1[4];
        #pragma unroll
        for (int j = 0; j < 4; j++) {
            ldg16_dev(av0[j], cur + aOff + j * 32);
            ldg16(bv0[j], W + wOff + j * 32);
        }
        #pragma unroll
        for (int j = 0; j < 4; j++) {
            ldg16_dev(av1[j], cur + aOff + BK + j * 32);
            ldg16(bv1[j], W + wOff + BK + j * 32);
        }

        int p = 0;
        #pragma unroll
        for (int it = 0; it < NITER; ++it) {
            // wait for THIS iter's 8 loads (oldest); 8 newer (next iter's) stay in flight
            if (it < NITER - 1) { asm volatile("s_waitcnt vmcnt(8)" ::: "memory"); }
            else                { asm volatile("s_waitcnt vmcnt(0)" ::: "memory"); }
            __builtin_amdgcn_sched_barrier(0);
            int4 (&av)[4] = (it & 1) ? av1 : av0;
            int4 (&bv)[4] = (it & 1) ? bv1 : bv0;
            #pragma unroll
            for (int j = 0; j < 4; j++) {
                *(int4*)&As[p][dst[j]] = av[j];
                *(int4*)&Bs[p][dst[j]] = bv[j];
            }
            __syncthreads();
            if (it + 2 < NITER) {
                const int kb2 = (it + 2) * BK;
                #pragma unroll
                for (int j = 0; j < 4; j++) {
                    ldg16_dev(av[j], cur + aOff + kb2 + j * 32);
                    ldg16(bv[j], W + wOff + kb2 + j * 32);
                }
            }
            #pragma unroll
            for (int ks = 0; ks < 4; ks++) {
                const int cb = ((ks * 32) + q * 8) ^ sw;
                bf16x8 a0 = *(const bf16x8*)&As[p][(wm * 32 +      r) * BK + cb];
                bf16x8 a1 = *(const bf16x8*)&As[p][(wm * 32 + 16 + r) * BK + cb];
                bf16x8 b0 = *(const bf16x8*)&Bs[p][(wn * 32 +      r) * BK + cb];
                bf16x8 b1 = *(const bf16x8*)&Bs[p][(wn * 32 + 16 + r) * BK + cb];
                acc[0][0] = __builtin_amdgcn_mfma_f32_16x16x32_bf16(a0, b0, acc[0][0], 0, 0, 0);
                acc[0][1] = __builtin_amdgcn_mfma_f32_16x16x32_bf16(a0, b1, acc[0][1], 0, 0, 0);
                acc[1][0] = __builtin_amdgcn_mfma_f32_16x16x32_bf16(a1, b0, acc[1][0], 0, 0, 0);
                acc[1][1] = __builtin_amdgcn_mfma_f32_16x16x32_bf16(a1, b1, acc[1][1], 0, 0, 0);
            }
            p ^= 1;
        }

        // ---- epilogue: tanh in registers. C/D layout: row = q*4+i, col = r. ----
        const int col0 = n0 + wn * 32 + r;
        const int col1 = col0 + 16;
        const float bb0 = bias[col0], bb1 = bias[col1];
        const float wa0 = Wact[col0], wa1 = Wact[col1];
        float fv0[2][4], fv1[2][4];
        #pragma unroll
        for (int mt = 0; mt < 2; mt++) {
            const int rowb = m0 + wm * 32 + mt * 16 + q * 4;
            #pragma unroll
            for (int i = 0; i < 4; i++) {
                float v0 = acc[mt][0][i] + bb0;
                float v1 = acc[mt][1][i] + bb1;
                if (pre) {
                    v0 += pre[(size_t)(rowb + i) * N + col0];
                    v1 += pre[(size_t)(rowb + i) * N + col1];
                }
                fv0[mt][i] = fast_tanh(v0);
                fv1[mt][i] = fast_tanh(v1);
            }
        }
        if (last) {
            #pragma unroll
            for (int mt = 0; mt < 2; mt++) {
                const int rowb = m0 + wm * 32 + mt * 16 + q * 4;
                #pragma unroll
                for (int i = 0; i < 4; i++) {
                    outHx[(size_t)(rowb + i) * N + col0] = fv0[mt][i];
                    outHx[(size_t)(rowb + i) * N + col1] = fv1[mt][i];
                }
            }
        }

        __syncthreads();                  // all waves' MFMA LDS reads done; reuse As
        u16*   Cs = (u16*)As;             // 64x64 bf16 = 8 KB staging for coalesced store
        float* sc = (float*)((char*)As + 8192);   // actor scratch (2 x 64 floats)
        if (!last) {
            #pragma unroll
            for (int mt = 0; mt < 2; mt++) {
                const int rl = wm * 32 + mt * 16 + q * 4;
                #pragma unroll
                for (int i = 0; i < 4; i++) {
                    Cs[(rl + i) * 64 + wn * 32 + r]      = f2b(fv0[mt][i]);
                    Cs[(rl + i) * 64 + wn * 32 + 16 + r] = f2b(fv1[mt][i]);
                }
            }
        }
        // actor head partials: shuffle-reduce 32 cols -> sc
        #pragma unroll
        for (int mt = 0; mt < 2; mt++)
            #pragma unroll
            for (int i = 0; i < 4; i++) {
                float v = fv0[mt][i] * wa0 + fv1[mt][i] * wa1;
                v += __shfl_xor(v, 1);
                v += __shfl_xor(v, 2);
                v += __shfl_xor(v, 4);
                v += __shfl_xor(v, 8);
                if (r == 0) sc[wn * 64 + wm * 32 + mt * 16 + q * 4 + i] = v;
            }
        __syncthreads();

        if (!last) {
            // coalesced hx store: 512 x dwordx4 per block (2 per thread)
            #pragma unroll
            for (int u2 = 0; u2 < 2; u2++) {
                const int ch = tid + u2 * 256;
                const int rw = ch >> 3, cc = ch & 7;
                intx4 val = *(const intx4*)&Cs[rw * 64 + cc * 8];
                stg16_dev(nxt + (size_t)(m0 + rw) * N + n0 + cc * 8, val);
            }
            VMEM_DRAIN();                 // hx stores at coherence point
            if (tid == 0)                 // arrive FIRST (peers can progress)...
                __hip_atomic_fetch_add(cnt, 1u, __ATOMIC_RELAXED, __HIP_MEMORY_SCOPE_AGENT);
        }
        if (tid < 64) {                   // ...then logits atomics (off the critical path)
            float v = sc[tid] + sc[64 + tid];
            atomicAdd(&logits[(size_t)s * B_DIM + m0 + tid], v);
        }
        if (!last) {
            VMEM_DRAIN();                 // atomics drained so counted waits stay exact
            if (tid == 0) {
                const unsigned tgt = 16u * (unsigned)(s + 1);
                while (__hip_atomic_load(cnt, __ATOMIC_RELAXED, __HIP_MEMORY_SCOPE_AGENT) < tgt)
                    __builtin_amdgcn_s_sleep(2);
            }
            __syncthreads();
            const u16* t = cur; cur = nxt; nxt = (u16*)t;
        }
    }
}

// fp32 -> bf16 bulk convert, z selects tensor
__global__ void convert_bf16(const float* __restrict__ s0, const float* __restrict__ s1,
                             const float* __restrict__ s2,
                             u16* __restrict__ d0, u16* __restrict__ d1, u16* __restrict__ d2,
                             int n)
{
    const int z = blockIdx.z;
    const float* s = (z == 0) ? s0 : (z == 1) ? s1 : s2;
    u16* d = (z == 0) ? d0 : (z == 1) ? d1 : d2;
    int i = (blockIdx.x * 256 + threadIdx.x) * 8;
    if (i < n) {
        float4 lo = *(const float4*)(s + i);
        float4 hi = *(const float4*)(s + i + 4);
        union { u16 h[8]; int4 v; } rr;
        rr.h[0] = f2b(lo.x); rr.h[1] = f2b(lo.y); rr.h[2] = f2b(lo.z); rr.h[3] = f2b(lo.w);
        rr.h[4] = f2b(hi.x); rr.h[5] = f2b(hi.y); rr.h[6] = f2b(hi.z); rr.h[7] = f2b(hi.w);
        *(int4*)(d + i) = rr.v;
    }
}

// Wsum = bf16(W_ih+W_hh), Whhb = bf16(W_hh), Wihb = bf16(W_ih); bsum = b_ih + b_hh
__global__ void prep_w(const float* __restrict__ Wih, const float* __restrict__ Whh,
                       u16* __restrict__ Wsum, u16* __restrict__ Whhb, u16* __restrict__ Wihb,
                       const float* __restrict__ bih, const float* __restrict__ bhh,
                       float* __restrict__ bsum, int n) {
    int i = blockIdx.x * 256 + threadIdx.x;
    if (i < n) {
        float a = Wih[i], b = Whh[i];
        Wsum[i] = f2b(a + b);
        Whhb[i] = f2b(b);
        Wihb[i] = f2b(a);
    }
    if (i < H_DIM) bsum[i] = bih[i] + bhh[i];
}

__global__ void sigmoid_kernel(const float* __restrict__ logits, const float* __restrict__ b_act,
                               float* __restrict__ out, int n) {
    int i = blockIdx.x * 256 + threadIdx.x;
    if (i < n) {
        float zv = logits[i] + b_act[0];
        out[i] = 1.0f / (1.0f + __expf(-zv));
    }
}

extern "C" void kernel_launch(void* const* d_in, const int* in_sizes, int n_in,
                              void* d_out, int out_size, void* d_ws, size_t ws_size,
                              hipStream_t stream) {
    (void)in_sizes; (void)n_in; (void)out_size;
    const int Bn = B_DIM, F = F_DIM, H = H_DIM;

    const float* xin[3] = {(const float*)d_in[0], (const float*)d_in[1], (const float*)d_in[2]};
    const float* W1[3]  = {(const float*)d_in[3], (const float*)d_in[7], (const float*)d_in[11]};
    const float* b1[3]  = {(const float*)d_in[4], (const float*)d_in[8], (const float*)d_in[12]};
    const float* W2[3]  = {(const float*)d_in[5], (const float*)d_in[9], (const float*)d_in[13]};
    const float* b2[3]  = {(const float*)d_in[6], (const float*)d_in[10], (const float*)d_in[14]};
    const float* W_ih   = (const float*)d_in[15];
    const float* W_hh   = (const float*)d_in[16];
    const float* b_ih   = (const float*)d_in[17];
    const float* b_hh   = (const float*)d_in[18];
    const float* W_act  = (const float*)d_in[19];
    const float* b_act  = (const float*)d_in[20];

    // ws layout (phased overlaps; base ~47 MB; optional bf16 pre-convert region above)
    const size_t MB = 1024 * 1024;
    char* ws = (char*)d_ws;
    u16*   xl     = (u16*)(ws + 0 * MB);
    u16*   xm     = (u16*)(ws + 4 * MB);
    u16*   xh     = (u16*)(ws + 8 * MB);    // hx ping
    u16*   hxB    = (u16*)(ws + 12 * MB);   // hx pong
    u16*   Wsum   = (u16*)(ws + 16 * MB);
    u16*   Whhb   = (u16*)(ws + 18 * MB);
    u16*   Wihb   = (u16*)(ws + 20 * MB);
    u16*   h1a    = (u16*)(ws + 22 * MB);   // live fc1 -> fc2
    u16*   h1b    = (u16*)(ws + 26 * MB);
    u16*   h1c    = (u16*)(ws + 30 * MB);
    float* pre_xh = (float*)(ws + 22 * MB); // written after fc2 (h1 dead)
    float* pre_xm = (float*)(ws + 30 * MB); // overlaps h1c (dead by then)
    float* pre_xl = (float*)(ws + 38 * MB);
    float* logits = (float*)(ws + 46 * MB);                        // 512 KB
    float* bsum   = (float*)(ws + 46 * MB + 512 * 1024);           // 4 KB
    unsigned* gsync = (unsigned*)(ws + 46 * MB + 516 * 1024);      // 4 KB (32 groups x 128 B)
    // optional bf16 pre-convert region (only if ws is big enough):
    u16* xb[3]  = {(u16*)(ws + 48 * MB), (u16*)(ws + 64 * MB), (u16*)(ws + 80 * MB)};   // 16 MB each
    u16* W1b[3] = {(u16*)(ws + 96 * MB), (u16*)(ws + 104 * MB), (u16*)(ws + 112 * MB)}; //  8 MB each
    u16* W2b[3] = {(u16*)(ws + 120 * MB), (u16*)(ws + 122 * MB), (u16*)(ws + 124 * MB)};//  2 MB each
    const bool big = ws_size >= (size_t)126 * MB;

    dim3 blk(256);
    dim3 grid3(16, 32, 3);

    (void)hipMemsetAsync(logits, 0, (size_t)NSTEP * Bn * sizeof(float), stream);
    (void)hipMemsetAsync(gsync, 0, 4096, stream);
    prep_w<<<dim3((H * H + 255) / 256), blk, 0, stream>>>(W_ih, W_hh, Wsum, Whhb, Wihb,
                                                          b_ih, b_hh, bsum, H * H);

    u16* h1[3] = {h1a, h1b, h1c};
    if (big) {
        // pre-convert x, W1, W2 to bf16 -> fc1/fc2 run the pure-bf16 staging path
        const int nX = Bn * F, nW1 = H * F, nW2 = H * H;
        convert_bf16<<<dim3((nX / 8 + 255) / 256, 1, 3), blk, 0, stream>>>(
            xin[0], xin[1], xin[2], xb[0], xb[1], xb[2], nX);
        convert_bf16<<<dim3((nW1 / 8 + 255) / 256, 1, 3), blk, 0, stream>>>(
            W1[0], W1[1], W1[2], W1b[0], W1b[1], W1b[2], nW1);
        convert_bf16<<<dim3((nW2 / 8 + 255) / 256, 1, 3), blk, 0, stream>>>(
            W2[0], W2[1], W2[2], W2b[0], W2b[1], W2b[2], nW2);
        gemm64<0,0,1,0><<<grid3, blk, 0, stream>>>(
            xb[0], xb[1], xb[2], W1b[0], W1b[1], W1b[2], b1[0], b1[1], b1[2],
            h1[0], h1[1], h1[2], H, F);
        gemm64<0,0,1,0><<<grid3, blk, 0, stream>>>(
            h1a, h1b, h1c, W2b[0], W2b[1], W2b[2], b2[0], b2[1], b2[2],
            xl, xm, xh, H, H);
    } else {
        // fallback: fp32 operands converted in-kernel (round-5 path)
        gemm64<1,1,1,0><<<grid3, blk, 0, stream>>>(
            xin[0], xin[1], xin[2], W1[0], W1[1], W1[2], b1[0], b1[1], b1[2],
            h1[0], h1[1], h1[2], H, F);
        gemm64<0,1,1,0><<<grid3, blk, 0, stream>>>(
            h1a, h1b, h1c, W2[0], W2[1], W2[2], b2[0], b2[1], b2[2],
            xl, xm, xh, H, H);
    }
    // pre (batched): pre_* = {xh,xm,xl} @ W_ih^T + b_ih (fp32 out)
    gemm64<0,0,0,1><<<grid3, blk, 0, stream>>>(
        xh, xm, xl, Wihb, Wihb, Wihb, b_ih, b_ih, b_ih,
        pre_xh, pre_xm, pre_xl, H, H);

    // persistent RNN: one plain launch (512 blocks == exact device capacity at 64 KiB LDS)
    float* outHx = (float*)d_out + (size_t)NSTEP * Bn;
    rnn_persist<<<dim3(512), dim3(256), 0, stream>>>(
        xh, hxB, Wsum, Whhb, bsum, b_hh, pre_xh, pre_xm, pre_xl,
        W_act, logits, outHx, gsync);

    sigmoid_kernel<<<dim3((NSTEP * Bn + 255) / 256), blk, 0, stream>>>(
        logits, b_act, (float*)d_out, NSTEP * Bn);
}